// Round 4
// baseline (962.375 us; speedup 1.0000x reference)
//
#include <hip/hip_runtime.h>
#include <stdint.h>

#define D_MODEL 1024
#define D_FF    4096
#define NE      8
#define T_TOK   4096
#define R_TOT   8192   // T_TOK * TOP_K, always exact (top-2 of 8 distinct)

typedef float f32x4 __attribute__((ext_vector_type(4)));
typedef __bf16 bf16x8 __attribute__((ext_vector_type(8)));
typedef unsigned short ushort_t;

__device__ __forceinline__ ushort_t f2bf(float f) {
    unsigned int u = __float_as_uint(f);
    u += 0x7FFFu + ((u >> 16) & 1u);   // round-to-nearest-even
    return (ushort_t)(u >> 16);
}

// async global->LDS, 16B per lane. Pass a WAVE-UNIFORM lds base; HW adds lane*16.
__device__ __forceinline__ void async16(const void* g, const void* l) {
    __builtin_amdgcn_global_load_lds(
        (const __attribute__((address_space(1))) unsigned int*)(uintptr_t)g,
        (__attribute__((address_space(3))) unsigned int*)(uintptr_t)l,
        16, 0, 0);
}

#define FENCE() asm volatile("" ::: "memory")
#define BAR()   do { FENCE(); __builtin_amdgcn_s_barrier(); FENCE(); } while (0)

// ---------------- gate: one wave per token ----------------
__global__ __launch_bounds__(256) void k_gate(
    const float* __restrict__ x, const float* __restrict__ Wg, const float* __restrict__ bg,
    int* __restrict__ topi, float* __restrict__ topw, int* __restrict__ counts)
{
    int wave = threadIdx.x >> 6, lane = threadIdx.x & 63;
    int t = blockIdx.x * 4 + wave;
    const float* xr = x + (size_t)t * D_MODEL;
    float acc[NE];
#pragma unroll
    for (int e = 0; e < NE; ++e) acc[e] = 0.f;
#pragma unroll
    for (int i = 0; i < D_MODEL / 64; ++i) {
        int k = i * 64 + lane;
        float xv = xr[k];
        const float4* wgp = (const float4*)(Wg + (size_t)k * NE);
        float4 w0 = wgp[0], w1 = wgp[1];
        acc[0] += xv * w0.x; acc[1] += xv * w0.y; acc[2] += xv * w0.z; acc[3] += xv * w0.w;
        acc[4] += xv * w1.x; acc[5] += xv * w1.y; acc[6] += xv * w1.z; acc[7] += xv * w1.w;
    }
#pragma unroll
    for (int off = 32; off >= 1; off >>= 1)
#pragma unroll
        for (int e = 0; e < NE; ++e) acc[e] += __shfl_down(acc[e], off, 64);
    if (lane == 0) {
        float l[NE], m = -1e30f;
#pragma unroll
        for (int e = 0; e < NE; ++e) { l[e] = acc[e] + bg[e]; m = fmaxf(m, l[e]); }
        float p[NE], Z = 0.f;
#pragma unroll
        for (int e = 0; e < NE; ++e) { p[e] = __expf(l[e] - m); Z += p[e]; }
        float invZ = 1.f / Z;
        int i0 = 0; float v0 = -1.f;
#pragma unroll
        for (int e = 0; e < NE; ++e) { p[e] *= invZ; if (p[e] > v0) { v0 = p[e]; i0 = e; } }
        int i1 = 0; float v1 = -1.f;
#pragma unroll
        for (int e = 0; e < NE; ++e) { if (e != i0 && p[e] > v1) { v1 = p[e]; i1 = e; } }
        float denom = 1.f / (v0 + v1 + 1e-6f);
        topi[t * 2 + 0] = i0; topi[t * 2 + 1] = i1;
        topw[t * 2 + 0] = v0 * denom; topw[t * 2 + 1] = v1 * denom;
        atomicAdd(&counts[i0], 1); atomicAdd(&counts[i1], 1);
    }
}

// ---------------- tiny scan ----------------
__global__ void k_scan(const int* __restrict__ counts, int* __restrict__ offsets,
                       int* __restrict__ cursors)
{
    if (threadIdx.x == 0) {
        int acc = 0;
        for (int e = 0; e < NE; ++e) { offsets[e] = acc; cursors[e] = acc; acc += counts[e]; }
    }
}

// ---------------- scatter tokens into expert buckets ----------------
__global__ __launch_bounds__(256) void k_scatter(
    const int* __restrict__ topi_in, const float* __restrict__ topw,
    int* __restrict__ cursors, int* __restrict__ btok, float* __restrict__ bw)
{
    int t = blockIdx.x * 256 + threadIdx.x;
    int* topi = (int*)topi_in;
#pragma unroll
    for (int k = 0; k < 2; ++k) {
        int e = topi[t * 2 + k];
        int p = atomicAdd(&cursors[e], 1);
        btok[p] = t;
        bw[p] = topw[t * 2 + k];
        topi[t * 2 + k] = p;     // pos map: token -> bucket row
    }
}

// ---------------- gather x rows (bucket order) + fp32->bf16 ----------------
__global__ __launch_bounds__(256) void k_gather(
    const float* __restrict__ x, const int* __restrict__ btok, ushort_t* __restrict__ Xg)
{
    int i = blockIdx.x;
    int t = btok[i];
    float4 v = ((const float4*)(x + (size_t)t * D_MODEL))[threadIdx.x];
    ushort4 o;
    o.x = f2bf(v.x); o.y = f2bf(v.y); o.z = f2bf(v.z); o.w = f2bf(v.w);
    ((ushort4*)(Xg + (size_t)i * D_MODEL))[threadIdx.x] = o;
}

// ---------------- weight transpose+convert: W[e][K][N] fp32 -> Wt[e][n'][K] bf16 ----------------
// mode 0: n' = n (W2). mode 1/2: W1/W3 columns interleaved at 128-col tiles:
// n' = (n>>7)*256 + (mode-1)*128 + (n&127)  -> W13t column-pair layout for fused gemm1.
__global__ __launch_bounds__(256) void k_transpose(
    const float* __restrict__ W, ushort_t* __restrict__ Wt, int K, int N, int mode)
{
    __shared__ ushort_t tile[64 * 76];
    int e = blockIdx.z;
    const float* We = W + (size_t)e * K * N;
    ushort_t* Wte = Wt + (size_t)e * K * (mode ? 2 * N : N);
    int nb = blockIdx.x * 64, kb = blockIdx.y * 64;
    int nbase = (mode == 0) ? nb : ((nb >> 7) * 256 + (mode - 1) * 128 + (nb & 64));
    int tn4 = (threadIdx.x & 15) * 4;
    int tk = threadIdx.x >> 4;
#pragma unroll
    for (int r = 0; r < 4; ++r) {
        int k = r * 16 + tk;
        float4 v = *(const float4*)(We + (size_t)(kb + k) * N + nb + tn4);
        tile[(tn4 + 0) * 76 + k] = f2bf(v.x);
        tile[(tn4 + 1) * 76 + k] = f2bf(v.y);
        tile[(tn4 + 2) * 76 + k] = f2bf(v.z);
        tile[(tn4 + 3) * 76 + k] = f2bf(v.w);
    }
    __syncthreads();
#pragma unroll
    for (int c = 0; c < 4; ++c) {
        int chunk = c * 256 + threadIdx.x;
        int n = chunk >> 4, kc = (chunk & 15) * 4;
        ushort4 o = *(const ushort4*)&tile[n * 76 + kc];
        *(ushort4*)(Wte + (size_t)(nbase + n) * K + kb + kc) = o;
    }
}

// =====================================================================
// m201-faithful schedule, grouped. 256x256 tile, 8 waves (2M x 4N),
// per-wave 128x64, BK=64 staged as K-HALVES (4 units/tile: Ah0,Bh0,Ah1,Bh1,
// one unit staged per phase). 4 phases/K-tile, each:
//   { ds_read one frag-cluster; stage 1 unit(t+1); [vmcnt(4) @P2,P4];
//     barrier; setprio(1); 16 MFMA; setprio(0); barrier }
// Every staged unit gets >=2-3 phases of flight before its vmcnt (the m218
// counted-vmcnt mechanism); vmcnt never drains to 0 mid-loop.
// LDS per K-half: [256][32] elem rows; 16B chunk q of row r at slot
// q ^ ((r>>1)&3)  -> ds_read_b128 2-way max (free), gload dest linear.
// Swizzle applied on global source, undone on read (both-sides rule).
// =====================================================================

// ---------------- grouped GEMM1: H = silu(Xg@W1 + b1) * (Xg@W3 + b3) ----------------
// B = W13t (N=8192 concat; 256-col tile = [128 W1-cols | same 128 W3-cols]).
// Epilogue: h3-waves (wn'>=2) park acc in LDS; h1-waves fuse silu*mul, store H.
__global__ __launch_bounds__(512, 2) void k_gemm1(
    const ushort_t* __restrict__ Xg, const ushort_t* __restrict__ W13t,
    const float* __restrict__ b1, const float* __restrict__ b3,
    const int* __restrict__ counts, const int* __restrict__ offsets,
    ushort_t* __restrict__ H)
{
    __shared__ __align__(16) ushort_t smem[65536];   // 128 KB: A[2][2][256][32] @0, B @32768

    int bx = blockIdx.x;
    int lx = (bx & 7) * 5 + (bx >> 3);     // bijective: 40 = 8 XCD * 5

    int tm = lx, e = 0, cnt = 0;
    for (; e < NE; ++e) {
        cnt = counts[e];
        int nt = (cnt + 255) >> 8;
        if (tm < nt) break;
        tm -= nt;
    }
    if (e >= NE) return;
    int row0 = offsets[e] + tm * 256;
    int rows_left = cnt - tm * 256;

    int tnp = blockIdx.y * 256;            // concat-B row base
    int tid = threadIdx.x, wave = tid >> 6, lane = tid & 63;
    int wmp = wave >> 2, wnp = wave & 3;   // 2M x 4N
    int wm = wmp * 128, wn = wnp * 64;
    int col = lane & 15, quad = lane >> 4;

    const ushort_t* We = W13t + (size_t)e * (2 * D_FF) * D_MODEL;

    // staging source lanes (2 instrs per wave per unit)
    const ushort_t* gA[2]; const ushort_t* gB[2]; unsigned su[2];
#pragma unroll
    for (int s = 0; s < 2; ++s) {
        int q = (wave * 2 + s) * 64 + lane;   // 16B-chunk index in 256x32 half
        int r = q >> 2;
        int c2 = (q & 3) ^ ((r >> 1) & 3);
        gA[s] = Xg + (size_t)(row0 + r) * D_MODEL + c2 * 8;
        gB[s] = We + (size_t)(tnp + r) * D_MODEL + c2 * 8;
        su[s] = (unsigned)(wave * 2 + s) * 512;   // elems within half region
    }

    int kswz = (quad ^ ((col >> 1) & 3)) * 8;
    unsigned aoff = (unsigned)(wm + col) * 32 + kswz;   // + i*512
    unsigned boff = (unsigned)(wn + col) * 32 + kswz;   // + j*512

    f32x4 acc[8][4];
#pragma unroll
    for (int i = 0; i < 8; ++i)
#pragma unroll
        for (int j = 0; j < 4; ++j) acc[i][j] = (f32x4){0.f, 0.f, 0.f, 0.f};

    // A half base: p*16384 + h*8192 ; B: +32768
#define STG_A(p, h, k0) do { \
        async16(gA[0] + (k0) + (h) * 32, &smem[(p) * 16384 + (h) * 8192 + su[0]]); \
        async16(gA[1] + (k0) + (h) * 32, &smem[(p) * 16384 + (h) * 8192 + su[1]]); } while (0)
#define STG_B(p, h, k0) do { \
        async16(gB[0] + (k0) + (h) * 32, &smem[32768 + (p) * 16384 + (h) * 8192 + su[0]]); \
        async16(gB[1] + (k0) + (h) * 32, &smem[32768 + (p) * 16384 + (h) * 8192 + su[1]]); } while (0)

    // prologue: tile 0 -> buf 0, all 4 units (8 loads)
    STG_A(0, 0, 0); STG_B(0, 0, 0); STG_A(0, 1, 0); STG_B(0, 1, 0);
    asm volatile("s_waitcnt vmcnt(4)" ::: "memory");   // Ah0,Bh0 landed; Ah1,Bh1 in flight
    BAR();

    const int NT = D_MODEL / 64;
    for (int t = 0; t < NT; ++t) {
        int p = t & 1, pn = p ^ 1;
        int k1 = (t + 1) * 64;
        bool pf = (t < NT - 1);
        const ushort_t* sa0 = &smem[p * 16384];            // kk0 A
        const ushort_t* sb0 = &smem[32768 + p * 16384];    // kk0 B
        const ushort_t* sa1 = sa0 + 8192;                  // kk1
        const ushort_t* sb1 = sb0 + 8192;
        bf16x8 a[4], b[4];

        // ---- P1: A[i0-3]@kk0 + B@kk0; stage Ah0(t+1) ----
#pragma unroll
        for (int i = 0; i < 4; ++i) a[i] = *(const bf16x8*)(sa0 + aoff + i * 512);
#pragma unroll
        for (int j = 0; j < 4; ++j) b[j] = *(const bf16x8*)(sb0 + boff + j * 512);
        if (pf) STG_A(pn, 0, k1);
        BAR();
        __builtin_amdgcn_s_setprio(1);
#pragma unroll
        for (int i = 0; i < 4; ++i)
#pragma unroll
            for (int j = 0; j < 4; ++j)
                acc[i][j] = __builtin_amdgcn_mfma_f32_16x16x32_bf16(a[i], b[j], acc[i][j], 0, 0, 0);
        __builtin_amdgcn_s_setprio(0);
        BAR();

        // ---- P2: A[i4-7]@kk0 (b reused); stage Bh0(t+1); vmcnt(4) ----
#pragma unroll
        for (int i = 0; i < 4; ++i) a[i] = *(const bf16x8*)(sa0 + aoff + (i + 4) * 512);
        if (pf) { STG_B(pn, 0, k1); asm volatile("s_waitcnt vmcnt(4)" ::: "memory"); }
        else    {                   asm volatile("s_waitcnt vmcnt(0)" ::: "memory"); }
        BAR();
        __builtin_amdgcn_s_setprio(1);
#pragma unroll
        for (int i = 0; i < 4; ++i)
#pragma unroll
            for (int j = 0; j < 4; ++j)
                acc[i + 4][j] = __builtin_amdgcn_mfma_f32_16x16x32_bf16(a[i], b[j], acc[i + 4][j], 0, 0, 0);
        __builtin_amdgcn_s_setprio(0);
        BAR();

        // ---- P3: A[i0-3]@kk1 + B@kk1; stage Ah1(t+1) ----
#pragma unroll
        for (int i = 0; i < 4; ++i) a[i] = *(const bf16x8*)(sa1 + aoff + i * 512);
#pragma unroll
        for (int j = 0; j < 4; ++j) b[j] = *(const bf16x8*)(sb1 + boff + j * 512);
        if (pf) STG_A(pn, 1, k1);
        BAR();
        __builtin_amdgcn_s_setprio(1);
#pragma unroll
        for (int i = 0; i < 4; ++i)
#pragma unroll
            for (int j = 0; j < 4; ++j)
                acc[i][j] = __builtin_amdgcn_mfma_f32_16x16x32_bf16(a[i], b[j], acc[i][j], 0, 0, 0);
        __builtin_amdgcn_s_setprio(0);
        BAR();

        // ---- P4: A[i4-7]@kk1; stage Bh1(t+1); vmcnt(4) ----
#pragma unroll
        for (int i = 0; i < 4; ++i) a[i] = *(const bf16x8*)(sa1 + aoff + (i + 4) * 512);
        if (pf) { STG_B(pn, 1, k1); asm volatile("s_waitcnt vmcnt(4)" ::: "memory"); }
        else    {                   asm volatile("s_waitcnt vmcnt(0)" ::: "memory"); }
        BAR();
        __builtin_amdgcn_s_setprio(1);
#pragma unroll
        for (int i = 0; i < 4; ++i)
#pragma unroll
            for (int j = 0; j < 4; ++j)
                acc[i + 4][j] = __builtin_amdgcn_mfma_f32_16x16x32_bf16(a[i], b[j], acc[i + 4][j], 0, 0, 0);
        __builtin_amdgcn_s_setprio(0);
        BAR();
    }
#undef STG_A
#undef STG_B

    // ---- epilogue: pair h1 (wn'<2) with h3 (wn'>=2) via LDS (2 passes, stride-65 pad) ----
    float* eL = (float*)smem;                 // 4 pairs x 64 x 65 f32 = 66.6 KB
    int isH3 = (wnp >= 2);
    int pair = wmp * 2 + (wnp & 1);
#pragma unroll
    for (int pass = 0; pass < 2; ++pass) {
        __syncthreads();
        if (isH3) {
#pragma unroll
            for (int il = 0; il < 4; ++il) {
                int i = pass * 4 + il;
#pragma unroll
                for (int j = 0; j < 4; ++j)
#pragma unroll
                    for (int r = 0; r < 4; ++r) {
                        int row_l = il * 16 + quad * 4 + r;
                        eL[(pair * 64 + row_l) * 65 + j * 16 + col] = acc[i][j][r];
                    }
            }
        }
        __syncthreads();
        if (!isH3) {
#pragma unroll
            for (int il = 0; il < 4; ++il) {
                int i = pass * 4 + il;
                int rbase = wm + i * 16 + quad * 4;
#pragma unroll
                for (int j = 0; j < 4; ++j) {
                    int n_log = blockIdx.y * 128 + (wnp & 1) * 64 + j * 16 + col;
                    float bias1 = b1[e * D_FF + n_log];
                    float bias3 = b3[e * D_FF + n_log];
#pragma unroll
                    for (int r = 0; r < 4; ++r) {
                        int row = rbase + r;
                        if (row < rows_left) {
                            float h1 = acc[i][j][r] + bias1;
                            float h3 = eL[(pair * 64 + il * 16 + quad * 4 + r) * 65 + j * 16 + col] + bias3;
                            float s = h1 / (1.f + __expf(-h1));
                            H[(size_t)(row0 + row) * D_FF + n_log] = f2bf(s * h3);
                        }
                    }
                }
            }
        }
    }
}

// ---------------- grouped GEMM2: Y[bucket_row] = H @ W2 + b2 ----------------
// 256x128 tile, 8 waves 4M x 2N (wave 64x64), BK=64 K-half units, 2 phases.
__global__ __launch_bounds__(512, 2) void k_gemm2(
    const ushort_t* __restrict__ H, const ushort_t* __restrict__ W2t,
    const float* __restrict__ b2,
    const int* __restrict__ counts, const int* __restrict__ offsets,
    float* __restrict__ Y)
{
    __shared__ __align__(16) ushort_t smem[49152];   // 96 KB: A[2][2][256][32] @0, B[2][2][128][32] @32768

    int bx = blockIdx.x;
    int lx = (bx & 7) * 5 + (bx >> 3);

    int tm = lx, e = 0, cnt = 0;
    for (; e < NE; ++e) {
        cnt = counts[e];
        int nt = (cnt + 255) >> 8;
        if (tm < nt) break;
        tm -= nt;
    }
    if (e >= NE) return;
    int row0 = offsets[e] + tm * 256;
    int rows_left = cnt - tm * 256;

    int tile_n = blockIdx.y * 128;
    int tid = threadIdx.x, wave = tid >> 6, lane = tid & 63;
    int wm = (wave >> 1) * 64, wn = (wave & 1) * 64;   // 4M x 2N
    int col = lane & 15, quad = lane >> 4;

    const ushort_t* W2e = W2t + (size_t)e * D_MODEL * D_FF;

    const ushort_t* gA[2]; const ushort_t* gB; unsigned su[2], sub;
#pragma unroll
    for (int s = 0; s < 2; ++s) {
        int q = (wave * 2 + s) * 64 + lane;
        int r = q >> 2;
        int c2 = (q & 3) ^ ((r >> 1) & 3);
        gA[s] = H + (size_t)(row0 + r) * D_FF + c2 * 8;
        su[s] = (unsigned)(wave * 2 + s) * 512;
    }
    {
        int q = wave * 64 + lane;              // 128x32 half: 8 instrs total
        int r = q >> 2;
        int c2 = (q & 3) ^ ((r >> 1) & 3);
        gB = W2e + (size_t)(tile_n + r) * D_FF + c2 * 8;
        sub = (unsigned)wave * 512;
    }

    int kswz = (quad ^ ((col >> 1) & 3)) * 8;
    unsigned aoff = (unsigned)(wm + col) * 32 + kswz;
    unsigned boff = (unsigned)(wn + col) * 32 + kswz;

    f32x4 acc[4][4];
#pragma unroll
    for (int i = 0; i < 4; ++i)
#pragma unroll
        for (int j = 0; j < 4; ++j) acc[i][j] = (f32x4){0.f, 0.f, 0.f, 0.f};

#define STG2_A(p, h, k0) do { \
        async16(gA[0] + (k0) + (h) * 32, &smem[(p) * 16384 + (h) * 8192 + su[0]]); \
        async16(gA[1] + (k0) + (h) * 32, &smem[(p) * 16384 + (h) * 8192 + su[1]]); } while (0)
#define STG2_B(p, h, k0) \
        async16(gB + (k0) + (h) * 32, &smem[32768 + (p) * 8192 + (h) * 4096 + sub])

    // prologue: tile 0 (6 loads)
    STG2_A(0, 0, 0); STG2_B(0, 0, 0); STG2_A(0, 1, 0); STG2_B(0, 1, 0);
    asm volatile("s_waitcnt vmcnt(3)" ::: "memory");
    BAR();

    const int NT = D_FF / 64;
    for (int t = 0; t < NT; ++t) {
        int p = t & 1, pn = p ^ 1;
        int k1 = (t + 1) * 64;
        bool pf = (t < NT - 1);
        const ushort_t* sa0 = &smem[p * 16384];
        const ushort_t* sb0 = &smem[32768 + p * 8192];
        const ushort_t* sa1 = sa0 + 8192;
        const ushort_t* sb1 = sb0 + 4096;
        bf16x8 a[4], b[4];

        // ---- Ph1: kk0; stage Ah0,Bh0(t+1); vmcnt(3) ----
#pragma unroll
        for (int i = 0; i < 4; ++i) a[i] = *(const bf16x8*)(sa0 + aoff + i * 512);
#pragma unroll
        for (int j = 0; j < 4; ++j) b[j] = *(const bf16x8*)(sb0 + boff + j * 512);
        if (pf) { STG2_A(pn, 0, k1); STG2_B(pn, 0, k1);
                  asm volatile("s_waitcnt vmcnt(3)" ::: "memory"); }
        else    { asm volatile("s_waitcnt vmcnt(0)" ::: "memory"); }
        BAR();
        __builtin_amdgcn_s_setprio(1);
#pragma unroll
        for (int i = 0; i < 4; ++i)
#pragma unroll
            for (int j = 0; j < 4; ++j)
                acc[i][j] = __builtin_amdgcn_mfma_f32_16x16x32_bf16(a[i], b[j], acc[i][j], 0, 0, 0);
        __builtin_amdgcn_s_setprio(0);
        BAR();

        // ---- Ph2: kk1; stage Ah1,Bh1(t+1); vmcnt(3) ----
#pragma unroll
        for (int i = 0; i < 4; ++i) a[i] = *(const bf16x8*)(sa1 + aoff + i * 512);
#pragma unroll
        for (int j = 0; j < 4; ++j) b[j] = *(const bf16x8*)(sb1 + boff + j * 512);
        if (pf) { STG2_A(pn, 1, k1); STG2_B(pn, 1, k1);
                  asm volatile("s_waitcnt vmcnt(3)" ::: "memory"); }
        else    { asm volatile("s_waitcnt vmcnt(0)" ::: "memory"); }
        BAR();
        __builtin_amdgcn_s_setprio(1);
#pragma unroll
        for (int i = 0; i < 4; ++i)
#pragma unroll
            for (int j = 0; j < 4; ++j)
                acc[i][j] = __builtin_amdgcn_mfma_f32_16x16x32_bf16(a[i], b[j], acc[i][j], 0, 0, 0);
        __builtin_amdgcn_s_setprio(0);
        BAR();
    }
#undef STG2_A
#undef STG2_B

    float bias[4];
#pragma unroll
    for (int j = 0; j < 4; ++j) bias[j] = b2[e * D_MODEL + tile_n + wn + j * 16 + col];

#pragma unroll
    for (int i = 0; i < 4; ++i) {
        int rbase = wm + i * 16 + quad * 4;
#pragma unroll
        for (int r = 0; r < 4; ++r) {
            int row = rbase + r;
            if (row < rows_left) {
                float* yrow = Y + (size_t)(row0 + row) * D_MODEL + tile_n + wn + col;
#pragma unroll
                for (int j = 0; j < 4; ++j)
                    yrow[j * 16] = acc[i][j][r] + bias[j];
            }
        }
    }
}

// ---------------- combine: out[t] = w0*Y[p0] + w1*Y[p1] ----------------
__global__ __launch_bounds__(256) void k_combine(
    const float* __restrict__ Y, const int* __restrict__ pos,
    const float* __restrict__ topw, float* __restrict__ out)
{
    int t = blockIdx.x, c = threadIdx.x;
    int p0 = pos[t * 2 + 0], p1 = pos[t * 2 + 1];
    float w0 = topw[t * 2 + 0], w1 = topw[t * 2 + 1];
    float4 y0 = ((const float4*)(Y + (size_t)p0 * D_MODEL))[c];
    float4 y1 = ((const float4*)(Y + (size_t)p1 * D_MODEL))[c];
    float4 o;
    o.x = w0 * y0.x + w1 * y1.x;
    o.y = w0 * y0.y + w1 * y1.y;
    o.z = w0 * y0.z + w1 * y1.z;
    o.w = w0 * y0.w + w1 * y1.w;
    ((float4*)(out + (size_t)t * D_MODEL))[c] = o;
}

extern "C" void kernel_launch(void* const* d_in, const int* in_sizes, int n_in,
                              void* d_out, int out_size, void* d_ws, size_t ws_size,
                              hipStream_t stream)
{
    const float* x  = (const float*)d_in[0];
    const float* Wg = (const float*)d_in[1];
    const float* bg = (const float*)d_in[2];
    const float* W1 = (const float*)d_in[3];
    const float* b1 = (const float*)d_in[4];
    const float* W3 = (const float*)d_in[5];
    const float* b3 = (const float*)d_in[6];
    const float* W2 = (const float*)d_in[7];
    const float* b2 = (const float*)d_in[8];
    float* out = (float*)d_out;

    char* ws = (char*)d_ws;
    int*   counts  = (int*)(ws + 0);
    int*   cursors = (int*)(ws + 32);
    int*   offsets = (int*)(ws + 64);
    int*   topi    = (int*)(ws + 256);
    float* topw    = (float*)(ws + 256 + 32768);
    int*   btok    = (int*)(ws + 256 + 65536);
    float* bw      = (float*)(ws + 256 + 98304);
    char* p = ws + 131328;
    ushort_t* Xg   = (ushort_t*)p;  p += (size_t)R_TOT * D_MODEL * 2;          // 16.78 MB
    ushort_t* Hb   = (ushort_t*)p;  p += (size_t)R_TOT * D_FF * 2;             // 67.1 MB
    ushort_t* W13t = (ushort_t*)p;  p += (size_t)NE * 2 * D_FF * D_MODEL * 2;  // 134.2 MB
    ushort_t* W2t  = (ushort_t*)p;                                             // 67.1 MB
    // Y overlays W13t (dead after k_gemm1): 8192*1024*4 = 33.5 MB
    float* Y = (float*)W13t;

    hipMemsetAsync(ws, 0, 64, stream);                       // counts + cursors

    k_gate<<<dim3(T_TOK / 4), dim3(256), 0, stream>>>(x, Wg, bg, topi, topw, counts);
    k_scan<<<dim3(1), dim3(64), 0, stream>>>(counts, offsets, cursors);
    k_scatter<<<dim3(T_TOK / 256), dim3(256), 0, stream>>>(topi, topw, cursors, btok, bw);
    k_gather<<<dim3(R_TOT), dim3(256), 0, stream>>>(x, btok, Xg);
    k_transpose<<<dim3(D_FF / 64, D_MODEL / 64, NE), dim3(256), 0, stream>>>(W1, W13t, D_MODEL, D_FF, 1);
    k_transpose<<<dim3(D_FF / 64, D_MODEL / 64, NE), dim3(256), 0, stream>>>(W3, W13t, D_MODEL, D_FF, 2);
    k_transpose<<<dim3(D_MODEL / 64, D_FF / 64, NE), dim3(256), 0, stream>>>(W2, W2t, D_FF, D_MODEL, 0);
    // grid.x = 40 = max 256-row tiles (sum ceil <= 39) and = 8 XCDs * 5 for the swizzle
    k_gemm1<<<dim3(40, (2 * D_FF) / 256), dim3(512), 0, stream>>>(Xg, W13t, b1, b3, counts, offsets, Hb);
    k_gemm2<<<dim3(40, D_MODEL / 128), dim3(512), 0, stream>>>(Hb, W2t, b2, counts, offsets, Y);
    k_combine<<<dim3(T_TOK), dim3(256), 0, stream>>>(Y, topi, topw, out);
}